// Round 3
// baseline (135.080 us; speedup 1.0000x reference)
//
#include <hip/hip_runtime.h>

// out[i, :] = weight[b[i], :]  (float32, Y_DIM=32), with out[0, :] = 0.
//
// Persistent grid-stride structure (matches the harness fill kernel, which
// demonstrates 6.7 TB/s on this machine):
//   - 2048 blocks (8 per CU, 32 waves/CU = full occupancy), 256 threads.
//   - Weight table (64 rows x 128 B = 8 KB) staged to LDS ONCE per block,
//     padded to 9-float4 row stride so 8 lane-groups reading 8 different
//     rows hit disjoint bank sets. One __syncthreads total per block.
//   - Then a 4x-unrolled grid-stride stream over all 8M float4s of output:
//     per element one 4 B b-load (8 lanes of a wave share one cell -> a
//     wave touches one 32 B segment, coalesced+broadcast), one LDS read,
//     one coalesced 16 B store. No block churn: each thread issues ~15
//     stores instead of 8-per-lifetime, and the kernarg/L1-warmup/barrier
//     cost is paid 2048 times instead of 3907 times with dead windows.

typedef float f32x4 __attribute__((ext_vector_type(4)));

#define WROWS 64
#define WPAD  9   // LDS row stride in float4s (128 B data + 16 B pad)

__global__ __launch_bounds__(256) void batch_effect_gather_kernel(
        const int* __restrict__ b,
        const f32x4* __restrict__ w4,    // weight as [64, 8] float4
        f32x4* __restrict__ out4,        // output as [N, 8] float4
        int n_vec) {                     // N * 8 float4s
    __shared__ f32x4 sw[WROWS * WPAD];   // 9216 B

    // Stage weight table -> LDS (512 float4s, 2 per thread, coalesced).
    const int tid = threadIdx.x;
#pragma unroll
    for (int t = tid; t < WROWS * 8; t += 256)
        sw[(t >> 3) * WPAD + (t & 7)] = w4[t];
    __syncthreads();

    const int stride = gridDim.x * 256;
    int g = blockIdx.x * 256 + tid;

    // Main loop: 4 independent elements in flight per iteration.
    for (; g + 3 * stride < n_vec; g += 4 * stride) {
        const int c0 = g, c1 = g + stride, c2 = g + 2 * stride, c3 = g + 3 * stride;
        const int b0 = b[c0 >> 3];
        const int b1 = b[c1 >> 3];
        const int b2 = b[c2 >> 3];
        const int b3 = b[c3 >> 3];
        f32x4 v0 = sw[b0 * WPAD + (c0 & 7)];
        f32x4 v1 = sw[b1 * WPAD + (c1 & 7)];
        f32x4 v2 = sw[b2 * WPAD + (c2 & 7)];
        f32x4 v3 = sw[b3 * WPAD + (c3 & 7)];
        if (c0 < 8) v0 = (f32x4){0.f, 0.f, 0.f, 0.f};   // out[0,:] = 0
        out4[c0] = v0;
        out4[c1] = v1;
        out4[c2] = v2;
        out4[c3] = v3;
    }
    // Tail.
    for (; g < n_vec; g += stride) {
        f32x4 v = sw[b[g >> 3] * WPAD + (g & 7)];
        if (g < 8) v = (f32x4){0.f, 0.f, 0.f, 0.f};
        out4[g] = v;
    }
}

extern "C" void kernel_launch(void* const* d_in, const int* in_sizes, int n_in,
                              void* d_out, int out_size, void* d_ws, size_t ws_size,
                              hipStream_t stream) {
    const int*   b  = (const int*)d_in[0];      // [N, 1] int32
    const f32x4* w4 = (const f32x4*)d_in[1];    // [64, 32] f32 -> [64, 8] float4
    f32x4* out4 = (f32x4*)d_out;                // [N, 32] f32 -> [N, 8] float4

    int n_vec = in_sizes[0] * 8;                // N cells * 8 float4s/row
    int blocks = 2048;                          // 8 per CU, grid-stride
    batch_effect_gather_kernel<<<blocks, 256, 0, stream>>>(b, w4, out4, n_vec);
}